// Round 2
// baseline (555.182 us; speedup 1.0000x reference)
//
#include <hip/hip_runtime.h>
#include <hip/hip_bf16.h>
#include <math.h>

#define NQ 8192
#define NK 524288
#define NB 128
#define NF 64
#define ND 128
#define EPSF 1e-8f

using bf16x8 = __attribute__((ext_vector_type(8))) short;
using f32x4  = __attribute__((ext_vector_type(4))) float;

__device__ __forceinline__ unsigned short f2bf(float x) {
    union { float f; unsigned int u; } v; v.f = x;
    unsigned int u = v.u;
    return (unsigned short)((u + 0x7FFFu + ((u >> 16) & 1u)) >> 16);
}

// Bfrag layout: [kc(6)][nt(8)][lane(64)][j(8)] bf16, B[k][n] with
// n = nt*16 + (lane&15), k = kc*32 + (lane>>4)*8 + j ; value = W[n][k]
__device__ __forceinline__ int frag_index(int k, int b) {
    int kc = k >> 5, kl = k & 31, quad = kl >> 3, j = kl & 7;
    int nt = b >> 4, ln = (quad << 4) | (b & 15);
    return ((kc * 8 + nt) * 64 + ln) * 8 + j;
}

// ---------------- prep: rotated probes, softplus weights, frag scatter ------
__global__ void prep_kernel(const float* __restrict__ angles,
                            const float* __restrict__ probes,
                            const float* __restrict__ kmw,
                            const float* __restrict__ qwr,
                            const float* __restrict__ qmw,
                            unsigned short* __restrict__ Bfrag,
                            float4* __restrict__ Ppack) {
    int t = threadIdx.x;          // 256 threads: 2 per bin
    int b = t >> 1;
    int half = t & 1;
    const float* pr = probes + b * ND;
    float ss = 0.f;
    for (int i = 0; i < ND; i += 4) {
        float4 v = *(const float4*)(pr + i);
        ss += v.x * v.x + v.y * v.y + v.z * v.z + v.w * v.w;
    }
    float scale = 1.f / (sqrtf(ss) + EPSF);
    int f0 = half * 32;
    for (int f = f0; f < f0 + 32; ++f) {
        float p0 = pr[2 * f] * scale;
        float p1 = pr[2 * f + 1] * scale;
        float c = cosf(angles[f]);
        float s = sinf(angles[f]);
        float rx = p0 * c - p1 * s;
        float ry = p0 * s + p1 * c;
        float x = qwr[b * NF + f];
        float sp = fmaxf(x, 0.f) + log1pf(expf(-fabsf(x)));   // softplus, stable
        float ew = -sp;
        float qw = qmw[b * NF + f];
        Ppack[b * NF + f] = make_float4(rx, ry, ew, qw);
        Bfrag[frag_index(2 * f, b)]     = f2bf(rx);
        Bfrag[frag_index(2 * f + 1, b)] = f2bf(ry);
        Bfrag[frag_index(128 + f, b)]   = f2bf(kmw[b * NF + f]);
    }
}

// ---------------- k_logits: (Nk x 192) @ (192 x 128) bf16 MFMA --------------
// A_ext row = [bf16(K row 0..127) | bf16(K_mag 0..63)]
__global__ __launch_bounds__(256, 2)
void k_gemm(const float* __restrict__ Kg,
            const unsigned short* __restrict__ Bfrag_g,
            const float* __restrict__ k_bias,
            float* __restrict__ out) {
    __shared__ unsigned short Alds[64 * 200];   // 64 rows x 192 cols, stride 200 shorts (400 B = 16*25, b128-aligned)
    __shared__ unsigned short Blds[6 * 8 * 64 * 8];
    int t = threadIdx.x;

    // stage B fragments (48 KB, L2-hot)
    {
        const uint4* src = (const uint4*)Bfrag_g;
        uint4* dst = (uint4*)Blds;
        #pragma unroll
        for (int i = 0; i < 12; ++i) dst[i * 256 + t] = src[i * 256 + t];
    }
    // stage A: 64 rows x 32 float4 (=128 fp32); full coverage, coalesced
    int rowbase = blockIdx.x * 64;
    #pragma unroll
    for (int i = 0; i < 8; ++i) {
        int idx = i * 256 + t;          // 0..2047
        int row = idx >> 5;             // 0..63
        int c = idx & 31;               // float4 index 0..31
        float4 v = *(const float4*)(Kg + (size_t)(rowbase + row) * ND + c * 4);
        unsigned int lo = (unsigned int)f2bf(v.x) | ((unsigned int)f2bf(v.y) << 16);
        unsigned int hi = (unsigned int)f2bf(v.z) | ((unsigned int)f2bf(v.w) << 16);
        *(unsigned int*)&Alds[row * 200 + c * 4]     = lo;
        *(unsigned int*)&Alds[row * 200 + c * 4 + 2] = hi;
        float m0 = sqrtf(v.x * v.x + v.y * v.y + EPSF);   // pair 2c
        float m1 = sqrtf(v.z * v.z + v.w * v.w + EPSF);   // pair 2c+1
        *(unsigned int*)&Alds[row * 200 + 128 + c * 2] =
            (unsigned int)f2bf(m0) | ((unsigned int)f2bf(m1) << 16);
    }
    __syncthreads();

    int lane = t & 63;
    int w = t >> 6;
    int m = lane & 15, quad = lane >> 4;
    f32x4 acc[8];
    #pragma unroll
    for (int i = 0; i < 8; ++i) acc[i] = (f32x4){0.f, 0.f, 0.f, 0.f};

    #pragma unroll
    for (int kc = 0; kc < 6; ++kc) {
        bf16x8 a = *(const bf16x8*)&Alds[(w * 16 + m) * 200 + kc * 32 + quad * 8];
        #pragma unroll
        for (int nt = 0; nt < 8; ++nt) {
            bf16x8 bb = *(const bf16x8*)&Blds[((kc * 8 + nt) * 64 + lane) * 8];
            acc[nt] = __builtin_amdgcn_mfma_f32_16x16x32_bf16(a, bb, acc[nt], 0, 0, 0);
        }
    }
    // epilogue: C row = quad*4+reg, col = lane&15
    int orow = rowbase + w * 16 + quad * 4;
    #pragma unroll
    for (int nt = 0; nt < 8; ++nt) {
        int col = nt * 16 + m;
        float bias = k_bias[col];
        #pragma unroll
        for (int r = 0; r < 4; ++r)
            out[(size_t)(orow + r) * NB + col] = acc[nt][r] + bias;
    }
}

// ---------------- q_logits: distance scoring, LDS-staged params -------------
__global__ __launch_bounds__(256, 3)
void q_kernel(const float* __restrict__ Qg,
              const float4* __restrict__ Ppack,
              const float* __restrict__ q_bias,
              float* __restrict__ outq) {
    __shared__ float Plds[32 * 260];   // 32 bins, stride 260 dwords (bank spread)
    __shared__ float Qlds[8 * 256];    // 8 rows x 64 float4 (qx,qy,qm,0)
    int t = threadIdx.x;
    int bg = blockIdx.x & 3;           // bin group (32 bins each)
    int rb = blockIdx.x >> 2;          // row block (32 rows each)

    #pragma unroll
    for (int i = 0; i < 8; ++i) {
        int idx = i * 256 + t;         // 0..2047
        int lb = idx >> 6, f = idx & 63;
        float4 v = Ppack[(bg * 32 + lb) * 64 + f];
        *(float4*)&Plds[lb * 260 + f * 4] = v;
    }

    int r = t >> 5;                    // local row 0..7
    int c = t & 31;                    // float4 index within row / local bin
    int lb = c;
    float bias = q_bias[bg * 32 + lb];

    for (int chunk = 0; chunk < 4; ++chunk) {
        __syncthreads();               // P ready / Qlds free
        int grow = rb * 32 + chunk * 8 + r;
        float4 v = *(const float4*)(Qg + (size_t)grow * ND + c * 4);
        float ss = v.x * v.x + v.y * v.y + v.z * v.z + v.w * v.w;
        #pragma unroll
        for (int msk = 1; msk < 32; msk <<= 1) ss += __shfl_xor(ss, msk);
        float inv = 1.f / (sqrtf(ss) + EPSF);
        float qx0 = v.x * inv, qy0 = v.y * inv;
        float qx1 = v.z * inv, qy1 = v.w * inv;
        float qm0 = sqrtf(qx0 * qx0 + qy0 * qy0 + EPSF);
        float qm1 = sqrtf(qx1 * qx1 + qy1 * qy1 + EPSF);
        *(float4*)&Qlds[r * 256 + c * 8]     = make_float4(qx0, qy0, qm0, 0.f);
        *(float4*)&Qlds[r * 256 + c * 8 + 4] = make_float4(qx1, qy1, qm1, 0.f);
        __syncthreads();

        float acc = 0.f;
        #pragma unroll 8
        for (int f = 0; f < 64; ++f) {
            float4 P  = *(const float4*)&Plds[lb * 260 + f * 4];
            float4 Qp = *(const float4*)&Qlds[r * 256 + f * 4];
            float dx = P.x - Qp.x, dy = P.y - Qp.y;
            float d = sqrtf(fmaf(dx, dx, fmaf(dy, dy, EPSF)));
            acc = fmaf(P.z, d, acc);
            acc = fmaf(P.w, Qp.z, acc);
        }
        outq[(size_t)grow * NB + bg * 32 + lb] = acc + bias;
    }
}

extern "C" void kernel_launch(void* const* d_in, const int* in_sizes, int n_in,
                              void* d_out, int out_size, void* d_ws, size_t ws_size,
                              hipStream_t stream) {
    const float* Q      = (const float*)d_in[0];
    const float* K      = (const float*)d_in[1];
    const float* angles = (const float*)d_in[2];
    const float* probes = (const float*)d_in[3];
    const float* kmw    = (const float*)d_in[4];
    const float* kb     = (const float*)d_in[5];
    const float* qwr    = (const float*)d_in[6];
    const float* qmw    = (const float*)d_in[7];
    const float* qb     = (const float*)d_in[8];
    float* out = (float*)d_out;

    unsigned short* Bfrag = (unsigned short*)d_ws;                 // 49152 B
    float4* Ppack = (float4*)((char*)d_ws + 65536);                // 131072 B

    prep_kernel<<<1, 256, 0, stream>>>(angles, probes, kmw, qwr, qmw, Bfrag, Ppack);
    k_gemm<<<NK / 64, 256, 0, stream>>>(K, Bfrag, kb, out);
    q_kernel<<<1024, 256, 0, stream>>>(Q, Ppack, qb, out + (size_t)NK * NB);
}